// Round 5
// baseline (152.368 us; speedup 1.0000x reference)
//
#include <hip/hip_runtime.h>
#include <hip/hip_bf16.h>
#include <math.h>

#define B_   16384
#define F_   26
#define E_   32
#define L_   50
#define CT_  13
#define D0_  909
#define D0P  928
#define D1_  512
#define D2_  256
#define V_   1000000
#define VE_  (V_ * E_)            // 32,000,000 elements

typedef __bf16 bf16x8 __attribute__((ext_vector_type(8)));
typedef float f32x4 __attribute__((ext_vector_type(4)));
typedef unsigned short u16x8 __attribute__((ext_vector_type(8)));

__device__ inline float bf2f(unsigned short u) {
    union { unsigned int i; float f; } v; v.i = ((unsigned int)u) << 16; return v.f;
}
__device__ inline unsigned short f2b(float f) {
    union { __hip_bfloat16 h; unsigned short u; } v;
    v.h = __float2bfloat16(f);
    return v.u;
}

__device__ inline void gld_lds16(const void* g, void* l) {
    __builtin_amdgcn_global_load_lds(
        (const __attribute__((address_space(1))) unsigned int*)g,
        (__attribute__((address_space(3))) unsigned int*)l, 16, 0, 0);
}

// ---------------- deep table fp32 -> bf16 (streaming, evict-first reads) ----------------
__global__ __launch_bounds__(256) void cvt_table(const float* __restrict__ dt,
                                                 unsigned short* __restrict__ tb) {
    size_t stride = (size_t)gridDim.x * 256 * 8;
    for (size_t i = ((size_t)blockIdx.x * 256 + threadIdx.x) * 8; i < (size_t)VE_; i += stride) {
        f32x4 a = __builtin_nontemporal_load((const f32x4*)(dt + i));
        f32x4 b = __builtin_nontemporal_load((const f32x4*)(dt + i + 4));
        u16x8 o;
        o[0] = f2b(a.x); o[1] = f2b(a.y); o[2] = f2b(a.z); o[3] = f2b(a.w);
        o[4] = f2b(b.x); o[5] = f2b(b.y); o[6] = f2b(b.z); o[7] = f2b(b.w);
        *(u16x8*)(tb + i) = o;     // normal store: want L3 residency for the gathers
    }
}

// ---------------- weight conversion (fp32 -> bf16, K padded), fused ----------------
#define W2N (D1_ * D0P)          // 475136
#define W3N (D2_ * D1_)          // 131072
__global__ __launch_bounds__(256) void cvt_weights(
    const float* __restrict__ w2, const float* __restrict__ w3,
    __hip_bfloat16* __restrict__ o2, __hip_bfloat16* __restrict__ o3)
{
    int i = blockIdx.x * 256 + threadIdx.x;
    if (i < W2N) {
        int r = i / D0P, c = i - r * D0P;
        float v = (c < D0_) ? w2[r * D0_ + c] : 0.f;
        o2[i] = __float2bfloat16(v);
    } else {
        int j = i - W2N;
        if (j < W3N) o3[j] = __float2bfloat16(w3[j]);
    }
}

// ---------------- embedding + concat + wide, bf16 table ----------------
// One wave per sample; 16 groups of 4 lanes; each group gathers one 64B bf16
// row per instruction (16B/lane) -> 16 rows in flight per VMEM instruction.
__global__ __launch_bounds__(256) void embed_bf16(
    const int* __restrict__ oi, const float* __restrict__ ox,
    const int* __restrict__ i1, const float* __restrict__ x1,
    const int* __restrict__ i2, const float* __restrict__ x2,
    const float* __restrict__ ct, const float* __restrict__ wtab,
    const unsigned short* __restrict__ tb,
    __hip_bfloat16* __restrict__ x0, float* __restrict__ wide)
{
    const int s    = blockIdx.x * 4 + (threadIdx.x >> 6);
    const int lane = threadIdx.x & 63;
    const int g    = lane >> 2;     // group 0..15
    const int l    = lane & 3;      // lane-in-group 0..3
    unsigned short* xrow = (unsigned short*)(x0 + (size_t)s * D0P);

    // ---- one-hot fields: group g handles fields g, g+16 ----
#pragma unroll
    for (int f0 = 0; f0 < 32; f0 += 16) {
        int f = f0 + g;
        if (f < F_) {
            int   idx = oi[s * F_ + f];
            float xv  = ox[s * F_ + f];
            u16x8 v = *(const u16x8*)(tb + (size_t)idx * E_ + l * 8);
            u16x8 o;
#pragma unroll
            for (int e = 0; e < 8; e++) o[e] = f2b(bf2f(v[e]) * xv);
            *(u16x8*)(xrow + f * E_ + l * 8) = o;
        }
    }

    // ---- multihot bags: group g handles j = g, g+16, g+32, g+48 ----
    float a1[8] = {0.f,0.f,0.f,0.f,0.f,0.f,0.f,0.f};
    float a2[8] = {0.f,0.f,0.f,0.f,0.f,0.f,0.f,0.f};
#pragma unroll
    for (int j0 = 0; j0 < 64; j0 += 16) {
        int j = j0 + g;
        if (j < L_) {
            int   k1  = i1[s * L_ + j];  float xv1 = x1[s * L_ + j];
            int   k2  = i2[s * L_ + j];  float xv2 = x2[s * L_ + j];
            u16x8 v1 = *(const u16x8*)(tb + (size_t)k1 * E_ + l * 8);
            u16x8 v2 = *(const u16x8*)(tb + (size_t)k2 * E_ + l * 8);
#pragma unroll
            for (int e = 0; e < 8; e++) {
                a1[e] = fmaf(bf2f(v1[e]), xv1, a1[e]);
                a2[e] = fmaf(bf2f(v2[e]), xv2, a2[e]);
            }
        }
    }
    // reduce across the 16 groups (lanes with equal l): xor lane bits 2..5
#pragma unroll
    for (int m = 4; m < 64; m <<= 1) {
#pragma unroll
        for (int e = 0; e < 8; e++) {
            a1[e] += __shfl_xor(a1[e], m);
            a2[e] += __shfl_xor(a2[e], m);
        }
    }
    if (g == 0) {
        u16x8 o;
#pragma unroll
        for (int e = 0; e < 8; e++) o[e] = f2b(a1[e]);
        *(u16x8*)(xrow + F_ * E_ + l * 8) = o;
    }
    if (g == 1) {
        u16x8 o;
#pragma unroll
        for (int e = 0; e < 8; e++) o[e] = f2b(a2[e]);
        *(u16x8*)(xrow + F_ * E_ + E_ + l * 8) = o;
    }
    // ---- continuous features + zero pad to D0P ----
    if (lane < E_) {
        float v = (lane < CT_) ? ct[s * CT_ + lane] : 0.f;
        xrow[F_ * E_ + 2 * E_ + lane] = f2b(v);
    }
    // ---- wide part (fp32 exact; wtab 4MB -> L2-resident) ----
    float acc = 0.f;
#pragma unroll
    for (int t = lane; t < F_ + 2 * L_; t += 64) {
        int idx; float xv;
        if (t < F_)            { idx = oi[s * F_ + t];            xv = ox[s * F_ + t]; }
        else if (t < F_ + L_)  { int j = t - F_;       idx = i1[s * L_ + j]; xv = x1[s * L_ + j]; }
        else                   { int j = t - F_ - L_;  idx = i2[s * L_ + j]; xv = x2[s * L_ + j]; }
        acc += wtab[idx] * xv;
    }
    for (int o = 32; o; o >>= 1) acc += __shfl_xor(acc, o);
    if (lane == 0) wide[s] = (float)E_ * acc;
}

// ---------------- embedding, fp32-table fallback (if ws too small) ----------------
__global__ __launch_bounds__(256) void embed_fp32(
    const int* __restrict__ oi, const float* __restrict__ ox,
    const int* __restrict__ i1, const float* __restrict__ x1,
    const int* __restrict__ i2, const float* __restrict__ x2,
    const float* __restrict__ ct, const float* __restrict__ wtab,
    const float* __restrict__ dtab,
    __hip_bfloat16* __restrict__ x0, float* __restrict__ wide)
{
    const int s    = blockIdx.x * 4 + (threadIdx.x >> 6);
    const int lane = threadIdx.x & 63;
    const int g    = lane >> 3;
    const int l    = lane & 7;
    unsigned short* xrow = (unsigned short*)(x0 + (size_t)s * D0P);
    const f32x4* dt4 = (const f32x4*)dtab;

#pragma unroll
    for (int f0 = 0; f0 < 32; f0 += 8) {
        int f = f0 + g;
        if (f < F_) {
            int   idx = oi[s * F_ + f];
            float xv  = ox[s * F_ + f];
            f32x4 v   = dt4[(size_t)idx * 8 + l];
            ushort4 o;
            o.x = f2b(v.x * xv); o.y = f2b(v.y * xv);
            o.z = f2b(v.z * xv); o.w = f2b(v.w * xv);
            *(ushort4*)(xrow + f * E_ + l * 4) = o;
        }
    }
    f32x4 a1 = {0.f,0.f,0.f,0.f}, a2 = {0.f,0.f,0.f,0.f};
#pragma unroll
    for (int j0 = 0; j0 < 56; j0 += 8) {
        int j = j0 + g;
        if (j < L_) {
            int k1 = i1[s * L_ + j];  float xv1 = x1[s * L_ + j];
            int k2 = i2[s * L_ + j];  float xv2 = x2[s * L_ + j];
            f32x4 v1 = dt4[(size_t)k1 * 8 + l];
            f32x4 v2 = dt4[(size_t)k2 * 8 + l];
            a1.x = fmaf(v1.x, xv1, a1.x); a1.y = fmaf(v1.y, xv1, a1.y);
            a1.z = fmaf(v1.z, xv1, a1.z); a1.w = fmaf(v1.w, xv1, a1.w);
            a2.x = fmaf(v2.x, xv2, a2.x); a2.y = fmaf(v2.y, xv2, a2.y);
            a2.z = fmaf(v2.z, xv2, a2.z); a2.w = fmaf(v2.w, xv2, a2.w);
        }
    }
#pragma unroll
    for (int m = 8; m < 64; m <<= 1) {
        a1.x += __shfl_xor(a1.x, m); a1.y += __shfl_xor(a1.y, m);
        a1.z += __shfl_xor(a1.z, m); a1.w += __shfl_xor(a1.w, m);
        a2.x += __shfl_xor(a2.x, m); a2.y += __shfl_xor(a2.y, m);
        a2.z += __shfl_xor(a2.z, m); a2.w += __shfl_xor(a2.w, m);
    }
    if (g == 0) {
        ushort4 o; o.x = f2b(a1.x); o.y = f2b(a1.y); o.z = f2b(a1.z); o.w = f2b(a1.w);
        *(ushort4*)(xrow + F_ * E_ + l * 4) = o;
    }
    if (g == 1) {
        ushort4 o; o.x = f2b(a2.x); o.y = f2b(a2.y); o.z = f2b(a2.z); o.w = f2b(a2.w);
        *(ushort4*)(xrow + F_ * E_ + E_ + l * 4) = o;
    }
    if (lane < E_) {
        float v = (lane < CT_) ? ct[s * CT_ + lane] : 0.f;
        xrow[F_ * E_ + 2 * E_ + lane] = f2b(v);
    }
    float acc = 0.f;
#pragma unroll
    for (int t = lane; t < F_ + 2 * L_; t += 64) {
        int idx; float xv;
        if (t < F_)            { idx = oi[s * F_ + t];            xv = ox[s * F_ + t]; }
        else if (t < F_ + L_)  { int j = t - F_;       idx = i1[s * L_ + j]; xv = x1[s * L_ + j]; }
        else                   { int j = t - F_ - L_;  idx = i2[s * L_ + j]; xv = x2[s * L_ + j]; }
        acc += wtab[idx] * xv;
    }
    for (int o = 32; o; o >>= 1) acc += __shfl_xor(acc, o);
    if (lane == 0) wide[s] = (float)E_ * acc;
}

// ---------------- bf16 MFMA GEMM (BM=64, BN=128):  C = act(A[M][K] * W[N][K]^T + b) ----------------
template<int N, int K, bool ACT>
__global__ __launch_bounds__(256) void gemm_bias(
    const __hip_bfloat16* __restrict__ A,
    const __hip_bfloat16* __restrict__ W,
    const float* __restrict__ bias,
    __hip_bfloat16* __restrict__ C, int MBLKS)
{
    __shared__ __hip_bfloat16 As[64 * 32];
    __shared__ __hip_bfloat16 Bs[128 * 32];

    const int bm   = blockIdx.x % MBLKS;
    const int bn   = blockIdx.x / MBLKS;
    const int tid  = threadIdx.x;
    const int lane = tid & 63;
    const int w    = tid >> 6;          // wave 0..3
    const int wm   = w >> 1, wn = w & 1;

    f32x4 acc[2][4] = {};

    const int srow = lane >> 2;         // 0..15
    const int scol = (lane & 3) * 8;
    const __hip_bfloat16* Aw  = A + ((size_t)bm * 64  + w * 16 + srow) * K + scol;
    const __hip_bfloat16* Ww0 = W + ((size_t)bn * 128 + w * 32 + srow) * K + scol;
    const __hip_bfloat16* Ww1 = Ww0 + (size_t)16 * K;
    char* AsW = (char*)As + w * 1024;   // 16 rows * 64B
    char* BsW = (char*)Bs + w * 2048;   // 32 rows * 64B

    const int fr = lane & 15;
    const int kg = (lane >> 4) * 8;

    for (int k0 = 0; k0 < K; k0 += 32) {
        gld_lds16(Aw  + k0, AsW);
        gld_lds16(Ww0 + k0, BsW);
        gld_lds16(Ww1 + k0, BsW + 1024);
        __syncthreads();

        bf16x8 af[2], bfv[4];
#pragma unroll
        for (int i = 0; i < 2; i++)
            af[i] = *(const bf16x8*)(As + (wm * 32 + i * 16 + fr) * 32 + kg);
#pragma unroll
        for (int j = 0; j < 4; j++)
            bfv[j] = *(const bf16x8*)(Bs + (wn * 64 + j * 16 + fr) * 32 + kg);
#pragma unroll
        for (int i = 0; i < 2; i++)
#pragma unroll
            for (int j = 0; j < 4; j++)
                acc[i][j] = __builtin_amdgcn_mfma_f32_16x16x32_bf16(af[i], bfv[j], acc[i][j], 0, 0, 0);
        __syncthreads();
    }

    float bv[4];
#pragma unroll
    for (int j = 0; j < 4; j++) bv[j] = bias[bn * 128 + wn * 64 + j * 16 + fr];
    const int crow0 = bm * 64 + wm * 32 + (lane >> 4) * 4;
    const int ccol0 = bn * 128 + wn * 64 + fr;
#pragma unroll
    for (int i = 0; i < 2; i++)
#pragma unroll
        for (int j = 0; j < 4; j++)
#pragma unroll
            for (int r = 0; r < 4; r++) {
                float v = acc[i][j][r] + bv[j];
                if (ACT) v = (v >= 0.f) ? v : 0.01f * v;
                C[(size_t)(crow0 + i * 16 + r) * N + ccol0 + j * 16] = __float2bfloat16(v);
            }
}

// ---------------- final 256->1 dot + sigmoid(+wide) ----------------
__global__ __launch_bounds__(256) void final_kernel(
    const __hip_bfloat16* __restrict__ h2, const float* __restrict__ w4,
    const float* __restrict__ b4, const float* __restrict__ wide,
    float* __restrict__ out)
{
    const int s    = blockIdx.x * 4 + (threadIdx.x >> 6);
    const int lane = threadIdx.x & 63;
    const unsigned short* hp = (const unsigned short*)(h2 + (size_t)s * D2_);
    ushort4 hv = *(const ushort4*)(hp + lane * 4);
    float4  wv = *(const float4*)(w4 + lane * 4);
    float acc = bf2f(hv.x) * wv.x + bf2f(hv.y) * wv.y + bf2f(hv.z) * wv.z + bf2f(hv.w) * wv.w;
    for (int o = 32; o; o >>= 1) acc += __shfl_xor(acc, o);
    if (lane == 0) {
        float x = acc + b4[0] + wide[s];
        out[s] = 1.f / (1.f + expf(-x));
    }
}

extern "C" void kernel_launch(void* const* d_in, const int* in_sizes, int n_in,
                              void* d_out, int out_size, void* d_ws, size_t ws_size,
                              hipStream_t stream) {
    const int*   oi  = (const int*)  d_in[0];
    const float* ox  = (const float*)d_in[1];
    const int*   i1  = (const int*)  d_in[2];
    const float* x1  = (const float*)d_in[3];
    const int*   i2  = (const int*)  d_in[4];
    const float* x2  = (const float*)d_in[5];
    const float* ct  = (const float*)d_in[6];
    const float* wt  = (const float*)d_in[7];
    const float* dt  = (const float*)d_in[8];
    const float* w2  = (const float*)d_in[9];
    const float* b2  = (const float*)d_in[10];
    const float* w3  = (const float*)d_in[11];
    const float* b3  = (const float*)d_in[12];
    const float* w4  = (const float*)d_in[13];
    const float* b4  = (const float*)d_in[14];
    float* out = (float*)d_out;

    const size_t TBBYTES = 64000000ULL;               // 1M * 32 * 2
    const size_t NEED    = TBBYTES + 56852480ULL;     // + x0/h1/h2/wide/w2b/w3b
    const bool   big     = ws_size >= NEED;

    char* ws = (char*)d_ws;
    size_t off = big ? TBBYTES : 0;
    unsigned short* tbl = (unsigned short*)ws;
    __hip_bfloat16* x0b = (__hip_bfloat16*)(ws + off);
    __hip_bfloat16* h1b = (__hip_bfloat16*)(ws + off + 30408704);
    __hip_bfloat16* h2b = (__hip_bfloat16*)(ws + off + 47185920);
    float*          wid = (float*)         (ws + off + 55574528);
    __hip_bfloat16* w2b = (__hip_bfloat16*)(ws + off + 55640064);
    __hip_bfloat16* w3b = (__hip_bfloat16*)(ws + off + 56590336);

    cvt_weights<<<(W2N + W3N + 255) / 256, 256, 0, stream>>>(w2, w3, w2b, w3b);
    if (big) {
        cvt_table<<<4096, 256, 0, stream>>>(dt, tbl);
        embed_bf16<<<4096, 256, 0, stream>>>(oi, ox, i1, x1, i2, x2, ct, wt, tbl, x0b, wid);
    } else {
        embed_fp32<<<4096, 256, 0, stream>>>(oi, ox, i1, x1, i2, x2, ct, wt, dt, x0b, wid);
    }
    gemm_bias<D1_, D0P, true ><<<256 * (D1_ / 128), 256, 0, stream>>>(x0b, w2b, b2, h1b, 256);
    gemm_bias<D2_, D1_, true ><<<256 * (D2_ / 128), 256, 0, stream>>>(h1b, w3b, b3, h2b, 256);
    final_kernel<<<4096, 256, 0, stream>>>(h2b, w4, b4, wid, out);
}

// Round 6
// 125.415 us; speedup vs baseline: 1.2149x; 1.2149x over previous
//
#include <hip/hip_runtime.h>
#include <hip/hip_bf16.h>
#include <math.h>

#define B_   16384
#define F_   26
#define E_   32
#define L_   50
#define CT_  13
#define D0_  909
#define D0P  928
#define D1_  512
#define D2_  256

typedef __bf16 bf16x8 __attribute__((ext_vector_type(8)));
typedef float f32x4 __attribute__((ext_vector_type(4)));

__device__ inline float bf2f(unsigned short u) {
    union { unsigned int i; float f; } v; v.i = ((unsigned int)u) << 16; return v.f;
}
__device__ inline unsigned short f2b(float f) {
    union { __hip_bfloat16 h; unsigned short u; } v;
    v.h = __float2bfloat16(f);
    return v.u;
}

__device__ inline void gld_lds16(const void* g, void* l) {
    __builtin_amdgcn_global_load_lds(
        (const __attribute__((address_space(1))) unsigned int*)g,
        (__attribute__((address_space(3))) unsigned int*)l, 16, 0, 0);
}

// ---------------- weight conversion (fp32 -> bf16, K padded), fused ----------------
#define W2N (D1_ * D0P)          // 475136
#define W3N (D2_ * D1_)          // 131072
__global__ __launch_bounds__(256) void cvt_weights(
    const float* __restrict__ w2, const float* __restrict__ w3,
    __hip_bfloat16* __restrict__ o2, __hip_bfloat16* __restrict__ o3)
{
    int i = blockIdx.x * 256 + threadIdx.x;
    if (i < W2N) {
        int r = i / D0P, c = i - r * D0P;
        float v = (c < D0_) ? w2[r * D0_ + c] : 0.f;
        o2[i] = __float2bfloat16(v);
    } else {
        int j = i - W2N;
        if (j < W3N) o3[j] = __float2bfloat16(w3[j]);
    }
}

// ---------------- embedding + concat + wide (max memory-level parallelism) ----------------
// One wave per sample; 8 groups of 8 lanes; ALL 18 row-gathers (4 onehot +
// 14 bag) are issued back-to-back before any consumption -> ~18 cache lines
// in flight per wave during the gather phase.
__global__ __launch_bounds__(256, 4) void embed_kernel(
    const int* __restrict__ oi, const float* __restrict__ ox,
    const int* __restrict__ i1, const float* __restrict__ x1,
    const int* __restrict__ i2, const float* __restrict__ x2,
    const float* __restrict__ ct, const float* __restrict__ wtab,
    const float* __restrict__ dtab,
    __hip_bfloat16* __restrict__ x0, float* __restrict__ wide)
{
    const int s    = blockIdx.x * 4 + (threadIdx.x >> 6);
    const int lane = threadIdx.x & 63;
    const int g    = lane >> 3;     // group 0..7
    const int l    = lane & 7;      // lane-in-group 0..7
    unsigned short* xrow = (unsigned short*)(x0 + (size_t)s * D0P);
    const f32x4* dt4 = (const f32x4*)dtab;   // row idx -> dt4[idx*8 + l]

    // ---- preload all indices & scales (branchless; invalid -> row 0, scale 0) ----
    int koh[4]; float soh[4];
#pragma unroll
    for (int t = 0; t < 4; t++) {
        int f = g + 8 * t; bool v = (f < F_);
        koh[t] = v ? oi[s * F_ + f] : 0;
        soh[t] = v ? ox[s * F_ + f] : 0.f;
    }
    int k1[7], k2[7]; float sc1[7], sc2[7];
#pragma unroll
    for (int t = 0; t < 7; t++) {
        int j = g + 8 * t; bool v = (j < L_);
        k1[t]  = v ? i1[s * L_ + j] : 0;
        sc1[t] = v ? x1[s * L_ + j] : 0.f;
        k2[t]  = v ? i2[s * L_ + j] : 0;
        sc2[t] = v ? x2[s * L_ + j] : 0.f;
    }

    // ---- issue ALL row gathers before consuming any ----
    f32x4 r1[7], r2[7], roh[4];
#pragma unroll
    for (int t = 0; t < 7; t++) r1[t] = dt4[(size_t)k1[t] * 8 + l];
#pragma unroll
    for (int t = 0; t < 7; t++) r2[t] = dt4[(size_t)k2[t] * 8 + l];
#pragma unroll
    for (int t = 0; t < 4; t++) roh[t] = dt4[(size_t)koh[t] * 8 + l];

    // ---- one-hot consume + store ----
#pragma unroll
    for (int t = 0; t < 4; t++) {
        int f = g + 8 * t;
        if (f < F_) {
            ushort4 o;
            o.x = f2b(roh[t].x * soh[t]); o.y = f2b(roh[t].y * soh[t]);
            o.z = f2b(roh[t].z * soh[t]); o.w = f2b(roh[t].w * soh[t]);
            *(ushort4*)(xrow + f * E_ + l * 4) = o;
        }
    }

    // ---- bag accumulate ----
    f32x4 a1 = {0.f,0.f,0.f,0.f}, a2 = {0.f,0.f,0.f,0.f};
#pragma unroll
    for (int t = 0; t < 7; t++) {
        a1.x = fmaf(r1[t].x, sc1[t], a1.x); a1.y = fmaf(r1[t].y, sc1[t], a1.y);
        a1.z = fmaf(r1[t].z, sc1[t], a1.z); a1.w = fmaf(r1[t].w, sc1[t], a1.w);
        a2.x = fmaf(r2[t].x, sc2[t], a2.x); a2.y = fmaf(r2[t].y, sc2[t], a2.y);
        a2.z = fmaf(r2[t].z, sc2[t], a2.z); a2.w = fmaf(r2[t].w, sc2[t], a2.w);
    }
    // reduce across the 8 groups (lanes with equal l)
#pragma unroll
    for (int m = 8; m < 64; m <<= 1) {
        a1.x += __shfl_xor(a1.x, m); a1.y += __shfl_xor(a1.y, m);
        a1.z += __shfl_xor(a1.z, m); a1.w += __shfl_xor(a1.w, m);
        a2.x += __shfl_xor(a2.x, m); a2.y += __shfl_xor(a2.y, m);
        a2.z += __shfl_xor(a2.z, m); a2.w += __shfl_xor(a2.w, m);
    }
    if (g == 0) {
        ushort4 o; o.x = f2b(a1.x); o.y = f2b(a1.y); o.z = f2b(a1.z); o.w = f2b(a1.w);
        *(ushort4*)(xrow + F_ * E_ + l * 4) = o;
    }
    if (g == 1) {
        ushort4 o; o.x = f2b(a2.x); o.y = f2b(a2.y); o.z = f2b(a2.z); o.w = f2b(a2.w);
        *(ushort4*)(xrow + F_ * E_ + E_ + l * 4) = o;
    }
    // ---- continuous features + zero pad to D0P ----
    if (lane < E_) {
        float v = (lane < CT_) ? ct[s * CT_ + lane] : 0.f;
        xrow[F_ * E_ + 2 * E_ + lane] = f2b(v);
    }
    // ---- wide part (fp32 exact; wtab 4MB -> L2/L3-resident) ----
    float acc = 0.f;
#pragma unroll
    for (int t = lane; t < F_ + 2 * L_; t += 64) {
        int idx; float xv;
        if (t < F_)            { idx = oi[s * F_ + t];            xv = ox[s * F_ + t]; }
        else if (t < F_ + L_)  { int j = t - F_;       idx = i1[s * L_ + j]; xv = x1[s * L_ + j]; }
        else                   { int j = t - F_ - L_;  idx = i2[s * L_ + j]; xv = x2[s * L_ + j]; }
        acc += wtab[idx] * xv;
    }
    for (int o = 32; o; o >>= 1) acc += __shfl_xor(acc, o);
    if (lane == 0) wide[s] = (float)E_ * acc;
}

// ---------------- bf16 MFMA GEMM (128x128 tile):  C = act(A[M][K] * W[N][K]^T + b) ----------------
template<int N, int K, bool ACT>
__global__ __launch_bounds__(256) void gemm_bias(
    const __hip_bfloat16* __restrict__ A,
    const __hip_bfloat16* __restrict__ W,
    const float* __restrict__ bias,
    __hip_bfloat16* __restrict__ C, int MBLKS)
{
    __shared__ __hip_bfloat16 As[128 * 32];
    __shared__ __hip_bfloat16 Bs[128 * 32];

    const int bm   = blockIdx.x % MBLKS;
    const int bn   = blockIdx.x / MBLKS;
    const int tid  = threadIdx.x;
    const int lane = tid & 63;
    const int w    = tid >> 6;          // wave 0..3
    const int wm   = w >> 1, wn = w & 1;

    f32x4 acc[4][4] = {};

    const int srow = lane >> 2;
    const int scol = (lane & 3) * 8;
    const __hip_bfloat16* Aw0 = A + ((size_t)bm * 128 + w * 32 + srow) * K + scol;
    const __hip_bfloat16* Aw1 = Aw0 + (size_t)16 * K;
    const __hip_bfloat16* Ww0 = W + ((size_t)bn * 128 + w * 32 + srow) * K + scol;
    const __hip_bfloat16* Ww1 = Ww0 + (size_t)16 * K;
    char* AsW = (char*)As + w * 2048;
    char* BsW = (char*)Bs + w * 2048;

    const int fr = lane & 15;
    const int kg = (lane >> 4) * 8;

    for (int k0 = 0; k0 < K; k0 += 32) {
        gld_lds16(Aw0 + k0, AsW);
        gld_lds16(Aw1 + k0, AsW + 1024);
        gld_lds16(Ww0 + k0, BsW);
        gld_lds16(Ww1 + k0, BsW + 1024);
        __syncthreads();

        bf16x8 af[4], bfv[4];
#pragma unroll
        for (int i = 0; i < 4; i++)
            af[i] = *(const bf16x8*)(As + (wm * 64 + i * 16 + fr) * 32 + kg);
#pragma unroll
        for (int i = 0; i < 4; i++)
            bfv[i] = *(const bf16x8*)(Bs + (wn * 64 + i * 16 + fr) * 32 + kg);
#pragma unroll
        for (int i = 0; i < 4; i++)
#pragma unroll
            for (int j = 0; j < 4; j++)
                acc[i][j] = __builtin_amdgcn_mfma_f32_16x16x32_bf16(af[i], bfv[j], acc[i][j], 0, 0, 0);
        __syncthreads();
    }

    float bv[4];
#pragma unroll
    for (int j = 0; j < 4; j++) bv[j] = bias[bn * 128 + wn * 64 + j * 16 + fr];
    const int crow0 = bm * 128 + wm * 64 + (lane >> 4) * 4;
    const int ccol0 = bn * 128 + wn * 64 + fr;
#pragma unroll
    for (int i = 0; i < 4; i++)
#pragma unroll
        for (int j = 0; j < 4; j++)
#pragma unroll
            for (int r = 0; r < 4; r++) {
                float v = acc[i][j][r] + bv[j];
                if (ACT) v = (v >= 0.f) ? v : 0.01f * v;
                C[(size_t)(crow0 + i * 16 + r) * N + ccol0 + j * 16] = __float2bfloat16(v);
            }
}

// ---------------- final 256->1 dot + sigmoid(+wide) ----------------
__global__ __launch_bounds__(256) void final_kernel(
    const __hip_bfloat16* __restrict__ h2, const float* __restrict__ w4,
    const float* __restrict__ b4, const float* __restrict__ wide,
    float* __restrict__ out)
{
    const int s    = blockIdx.x * 4 + (threadIdx.x >> 6);
    const int lane = threadIdx.x & 63;
    const unsigned short* hp = (const unsigned short*)(h2 + (size_t)s * D2_);
    ushort4 hv = *(const ushort4*)(hp + lane * 4);
    float4  wv = *(const float4*)(w4 + lane * 4);
    float acc = bf2f(hv.x) * wv.x + bf2f(hv.y) * wv.y + bf2f(hv.z) * wv.z + bf2f(hv.w) * wv.w;
    for (int o = 32; o; o >>= 1) acc += __shfl_xor(acc, o);
    if (lane == 0) {
        float x = acc + b4[0] + wide[s];
        out[s] = 1.f / (1.f + expf(-x));
    }
}

extern "C" void kernel_launch(void* const* d_in, const int* in_sizes, int n_in,
                              void* d_out, int out_size, void* d_ws, size_t ws_size,
                              hipStream_t stream) {
    const int*   oi  = (const int*)  d_in[0];
    const float* ox  = (const float*)d_in[1];
    const int*   i1  = (const int*)  d_in[2];
    const float* x1  = (const float*)d_in[3];
    const int*   i2  = (const int*)  d_in[4];
    const float* x2  = (const float*)d_in[5];
    const float* ct  = (const float*)d_in[6];
    const float* wt  = (const float*)d_in[7];
    const float* dt  = (const float*)d_in[8];
    const float* w2  = (const float*)d_in[9];
    const float* b2  = (const float*)d_in[10];
    const float* w3  = (const float*)d_in[11];
    const float* b3  = (const float*)d_in[12];
    const float* w4  = (const float*)d_in[13];
    const float* b4  = (const float*)d_in[14];
    float* out = (float*)d_out;

    char* ws = (char*)d_ws;
    __hip_bfloat16* x0b = (__hip_bfloat16*)(ws);                    // 16384*928*2  = 30,408,704
    __hip_bfloat16* h1b = (__hip_bfloat16*)(ws + 30408704);         // 16384*512*2  = 16,777,216
    __hip_bfloat16* h2b = (__hip_bfloat16*)(ws + 47185920);         // 16384*256*2  =  8,388,608
    float*          wid = (float*)         (ws + 55574528);         // 16384*4      =     65,536
    __hip_bfloat16* w2b = (__hip_bfloat16*)(ws + 55640064);         // 512*928*2    =    950,272
    __hip_bfloat16* w3b = (__hip_bfloat16*)(ws + 56590336);         // 256*512*2    =    262,144

    cvt_weights<<<(W2N + W3N + 255) / 256, 256, 0, stream>>>(w2, w3, w2b, w3b);
    embed_kernel<<<4096, 256, 0, stream>>>(oi, ox, i1, x1, i2, x2, ct, wt, dt, x0b, wid);
    gemm_bias<D1_, D0P, true ><<<128 * (D1_ / 128), 256, 0, stream>>>(x0b, w2b, b2, h1b, 128);
    gemm_bias<D2_, D1_, true ><<<128 * (D2_ / 128), 256, 0, stream>>>(h1b, w3b, b3, h2b, 128);
    final_kernel<<<4096, 256, 0, stream>>>(h2b, w4, b4, wid, out);
}